// Round 1
// baseline (673.743 us; speedup 1.0000x reference)
//
#include <hip/hip_runtime.h>

#define NN 8192
#define DD 256
#define FF 128
#define BB 4096
#define NSPLIT 8
#define KCHUNK (NN / NSPLIT)   // 1024 keys per split-K chunk
#define QBLKS 128              // ceil(4096/32)

// ---------------- small setup kernels: unique(x) compaction ----------------

__global__ __launch_bounds__(256) void init_kernel(int* flags, int* cnt) {
  int i = blockIdx.x * 256 + threadIdx.x;   // grid covers exactly NN
  flags[i] = 0;
  if (i == 0) *cnt = 0;
}

__global__ __launch_bounds__(256) void scatter_kernel(const int* __restrict__ x, int* flags) {
  int b = blockIdx.x * 256 + threadIdx.x;   // grid covers exactly BB
  flags[x[b]] = 1;
}

__global__ __launch_bounds__(256) void compact_kernel(const int* __restrict__ flags, int* cnt,
                                                      int* list, int* slot) {
  int i = blockIdx.x * 256 + threadIdx.x;
  if (flags[i]) {
    int pos = atomicAdd(cnt, 1);  // order irrelevant: h stored by slot, looked up via slot[]
    list[pos] = i;
    slot[i] = pos;
  }
}

// ---------------- Wh = embedding @ W  (8192x256 @ 256x128, fp32) ----------------

__global__ __launch_bounds__(256) void wh_kernel(const float* __restrict__ emb,
                                                 const float* __restrict__ W,
                                                 float* __restrict__ Wh) {
  __shared__ float Es[32 * 65];    // stride 65: conflict-free column reads
  __shared__ float Ws[64 * 128];
  const int t = threadIdx.x;
  const int r0 = blockIdx.x * 32;
  const int rg = t >> 5;           // 0..7 -> rows 4rg..4rg+3
  const int cg = t & 31;           // cols 4cg..4cg+3
  float4 acc[4] = {{0,0,0,0},{0,0,0,0},{0,0,0,0},{0,0,0,0}};
  for (int kc = 0; kc < DD; kc += 64) {
    __syncthreads();
    for (int i = 0; i < 8; ++i) {                 // stage emb tile 32x64
      int idx = t + 256 * i;
      int r = idx >> 6, k = idx & 63;
      Es[r * 65 + k] = emb[(r0 + r) * DD + kc + k];
    }
    for (int i = 0; i < 8; ++i) {                 // stage W chunk 64x128
      int idx = t + 256 * i;
      int kr = idx >> 5, c4 = (idx & 31) * 4;
      *(float4*)&Ws[kr * 128 + c4] = *(const float4*)&W[(kc + kr) * 128 + c4];
    }
    __syncthreads();
    for (int k = 0; k < 64; ++k) {
      float4 b = *(const float4*)&Ws[k * 128 + cg * 4];
#pragma unroll
      for (int i = 0; i < 4; ++i) {
        float a = Es[(rg * 4 + i) * 65 + k];
        acc[i].x += a * b.x; acc[i].y += a * b.y;
        acc[i].z += a * b.z; acc[i].w += a * b.w;
      }
    }
  }
#pragma unroll
  for (int i = 0; i < 4; ++i)
    *(float4*)&Wh[(r0 + rg * 4 + i) * FF + cg * 4] = acc[i];
}

// ---------------- flash attention over masked S (split-K by 8) ----------------
// alpha[i] cancels in row softmax; masked entries get weight exactly 0.
// Block: 256 threads, 32 query rows (gathered via list), keys [chunk*1024, +1024).
// Thread owns 2 query rows (qi0,qi1) for both S and PV phases (scale stays in regs).

__global__ __launch_bounds__(256) void attn_kernel(
    const float* __restrict__ Wh, const int* __restrict__ adj,
    const int* __restrict__ list, const int* __restrict__ cntp,
    float* __restrict__ Opart, float* __restrict__ mpart, float* __restrict__ lpart) {
  __shared__ float Qs[32 * 132];          // stride 132: 8 distinct banks across qi
  __shared__ float Ks[64 * 132];
  __shared__ float Ps[32 * 65];
  __shared__ unsigned char adjb[32 * 64];
  __shared__ int nid[32];

  const int t = threadIdx.x;
  const int cnt = *cntp;
  const int qblk = blockIdx.x >> 3;
  const int chunk = blockIdx.x & 7;
  const int qbase = qblk * 32;
  if (qbase >= cnt) return;               // uniform branch: whole block exits

  if (t < 32) nid[t] = list[min(qbase + t, cnt - 1)];  // clamp partial block (dup rows land in unused h slots)
  __syncthreads();

  for (int i = 0; i < 4; ++i) {           // stage Q tile 32x128
    int idx = t + 256 * i;
    int r = idx >> 5, c4 = (idx & 31) * 4;
    *(float4*)&Qs[r * 132 + c4] = *(const float4*)&Wh[nid[r] * FF + c4];
  }

  const int qh = t >> 4;                  // 0..15 -> rows 2qh, 2qh+1
  const int qi0 = qh * 2, qi1 = qi0 + 1;
  const int jj = t & 15;
  const int fo = jj * 4;

  float m0 = -1e30f, l0 = 0.f, m1 = -1e30f, l1 = 0.f;
  float4 O00 = {0,0,0,0}, O01 = {0,0,0,0}, O10 = {0,0,0,0}, O11 = {0,0,0,0};

  const int kt0 = chunk * KCHUNK;
  for (int kt = kt0; kt < kt0 + KCHUNK; kt += 64) {
    __syncthreads();                                      // prev-iter Ks/Ps reads done
    for (int i = 0; i < 8; ++i) {                         // stage K tile 64x128
      int idx = t + 256 * i;
      int r = idx >> 5, c4 = (idx & 31) * 4;
      *(float4*)&Ks[r * 132 + c4] = *(const float4*)&Wh[(kt + r) * FF + c4];
    }
    for (int i = 0; i < 8; ++i) {                         // stage adj tile as bytes
      int idx = t + 256 * i;
      int r = idx >> 6, j = idx & 63;
      adjb[r * 64 + j] = (unsigned char)(adj[nid[r] * NN + kt + j] > 0);
    }
    __syncthreads();

    // ---- S = Q·K^T : 2 rows x 4 cols per thread, float4 along k ----
    float s0[4] = {0,0,0,0}, s1[4] = {0,0,0,0};
    for (int k4 = 0; k4 < 32; ++k4) {
      float4 q0 = *(const float4*)&Qs[qi0 * 132 + k4 * 4];
      float4 q1 = *(const float4*)&Qs[qi1 * 132 + k4 * 4];
#pragma unroll
      for (int m4 = 0; m4 < 4; ++m4) {
        float4 kv = *(const float4*)&Ks[(jj + 16 * m4) * 132 + k4 * 4];
        s0[m4] += q0.x*kv.x + q0.y*kv.y + q0.z*kv.z + q0.w*kv.w;
        s1[m4] += q1.x*kv.x + q1.y*kv.y + q1.z*kv.z + q1.w*kv.w;
      }
    }

    // ---- online softmax (mask -> p=0 explicitly; no exp-of-0 trap) ----
    float ts0 = -1e30f, ts1 = -1e30f;
    bool b0[4], b1[4];
#pragma unroll
    for (int m4 = 0; m4 < 4; ++m4) {
      int j = jj + 16 * m4;
      b0[m4] = adjb[qi0 * 64 + j] != 0;
      b1[m4] = adjb[qi1 * 64 + j] != 0;
      ts0 = fmaxf(ts0, b0[m4] ? s0[m4] : -1e30f);
      ts1 = fmaxf(ts1, b1[m4] ? s1[m4] : -1e30f);
    }
#pragma unroll
    for (int w = 1; w <= 8; w <<= 1) {                    // 16-lane butterfly (row group)
      ts0 = fmaxf(ts0, __shfl_xor(ts0, w));
      ts1 = fmaxf(ts1, __shfl_xor(ts1, w));
    }
    float nm0 = fmaxf(m0, ts0), nm1 = fmaxf(m1, ts1);
    float sc0 = expf(m0 - nm0), sc1 = expf(m1 - nm1);
    float tl0 = 0.f, tl1 = 0.f;
#pragma unroll
    for (int m4 = 0; m4 < 4; ++m4) {
      int j = jj + 16 * m4;
      float p0 = b0[m4] ? expf(s0[m4] - nm0) : 0.f;
      float p1 = b1[m4] ? expf(s1[m4] - nm1) : 0.f;
      tl0 += p0; tl1 += p1;
      Ps[qi0 * 65 + j] = p0;
      Ps[qi1 * 65 + j] = p1;
    }
#pragma unroll
    for (int w = 1; w <= 8; w <<= 1) {
      tl0 += __shfl_xor(tl0, w);
      tl1 += __shfl_xor(tl1, w);
    }
    l0 = l0 * sc0 + tl0; m0 = nm0;
    l1 = l1 * sc1 + tl1; m1 = nm1;
    __syncthreads();                                      // Ps visible to PV readers

    // ---- PV: O = diag(sc)*O + P·K ----
    O00.x *= sc0; O00.y *= sc0; O00.z *= sc0; O00.w *= sc0;
    O01.x *= sc0; O01.y *= sc0; O01.z *= sc0; O01.w *= sc0;
    O10.x *= sc1; O10.y *= sc1; O10.z *= sc1; O10.w *= sc1;
    O11.x *= sc1; O11.y *= sc1; O11.z *= sc1; O11.w *= sc1;
    for (int j = 0; j < 64; ++j) {
      float p0 = Ps[qi0 * 65 + j];
      float p1 = Ps[qi1 * 65 + j];
      float4 ka = *(const float4*)&Ks[j * 132 + fo];
      float4 kb = *(const float4*)&Ks[j * 132 + fo + 64];
      O00.x += p0 * ka.x; O00.y += p0 * ka.y; O00.z += p0 * ka.z; O00.w += p0 * ka.w;
      O01.x += p0 * kb.x; O01.y += p0 * kb.y; O01.z += p0 * kb.z; O01.w += p0 * kb.w;
      O10.x += p1 * ka.x; O10.y += p1 * ka.y; O10.z += p1 * ka.z; O10.w += p1 * ka.w;
      O11.x += p1 * kb.x; O11.y += p1 * kb.y; O11.z += p1 * kb.z; O11.w += p1 * kb.w;
    }
  }

  const int row0 = qbase + qi0, row1 = qbase + qi1;
  float* Op = Opart + (size_t)chunk * 4096 * FF;
  *(float4*)&Op[row0 * FF + fo]      = O00;
  *(float4*)&Op[row0 * FF + fo + 64] = O01;
  *(float4*)&Op[row1 * FF + fo]      = O10;
  *(float4*)&Op[row1 * FF + fo + 64] = O11;
  if (jj == 0) {
    mpart[chunk * 4096 + row0] = m0; lpart[chunk * 4096 + row0] = l0;
    mpart[chunk * 4096 + row1] = m1; lpart[chunk * 4096 + row1] = l1;
  }
}

// ---------------- merge split-K partials, normalize by l, elu ----------------

__global__ __launch_bounds__(128) void combine_kernel(
    const float* __restrict__ Opart, const float* __restrict__ mpart,
    const float* __restrict__ lpart, float* __restrict__ h) {
  const int r = blockIdx.x;       // 0..4095 (rows >= cnt produce unused junk)
  const int t = threadIdx.x;
  float mstar = -1e30f;
#pragma unroll
  for (int c = 0; c < NSPLIT; ++c) mstar = fmaxf(mstar, mpart[c * 4096 + r]);
  float lstar = 0.f, acc = 0.f;
#pragma unroll
  for (int c = 0; c < NSPLIT; ++c) {
    float w = expf(mpart[c * 4096 + r] - mstar);
    lstar += w * lpart[c * 4096 + r];
    acc += w * Opart[((size_t)c * 4096 + r) * FF + t];
  }
  float v = acc / fmaxf(lstar, 1e-30f);
  h[r * FF + t] = v > 0.f ? v : expm1f(v);   // elu
}

// ---------------- gather by x, L2-normalize ----------------

__global__ __launch_bounds__(128) void out_kernel(const int* __restrict__ x,
                                                  const int* __restrict__ slot,
                                                  const float* __restrict__ h,
                                                  float* __restrict__ out) {
  const int b = blockIdx.x, t = threadIdx.x;
  const int s = slot[x[b]];
  float v = h[s * FF + t];
  float ss = v * v;
#pragma unroll
  for (int w = 1; w <= 32; w <<= 1) ss += __shfl_xor(ss, w);  // 64-lane wave sum
  __shared__ float red[2];
  if ((t & 63) == 0) red[t >> 6] = ss;
  __syncthreads();
  float tot = red[0] + red[1];
  float scale = 1.f / fmaxf(sqrtf(tot), 1e-12f);
  out[b * FF + t] = v * scale;
}

// ---------------- launch ----------------

extern "C" void kernel_launch(void* const* d_in, const int* in_sizes, int n_in,
                              void* d_out, int out_size, void* d_ws, size_t ws_size,
                              hipStream_t stream) {
  const int*   x   = (const int*)d_in[0];
  const int*   adj = (const int*)d_in[1];
  const float* emb = (const float*)d_in[2];
  const float* W   = (const float*)d_in[3];
  float* out = (float*)d_out;

  // ws layout (float units)
  float* ws    = (float*)d_ws;
  float* Wh    = ws;                       // 8192*128   = 1,048,576
  float* h     = ws + 1048576;             // 4096*128   =   524,288
  float* Opart = ws + 1572864;             // 8*4096*128 = 4,194,304
  float* mpart = ws + 5767168;             // 8*4096
  float* lpart = ws + 5799936;             // 8*4096
  int*   iws   = (int*)(ws + 5832704);
  int*   flags = iws;                      // 8192
  int*   list  = iws + 8192;               // 4096
  int*   slot  = iws + 8192 + 4096;        // 8192
  int*   cnt   = iws + 8192 + 4096 + 8192; // 1
  (void)in_sizes; (void)n_in; (void)out_size; (void)ws_size;

  hipLaunchKernelGGL(init_kernel,    dim3(NN / 256), dim3(256), 0, stream, flags, cnt);
  hipLaunchKernelGGL(scatter_kernel, dim3(BB / 256), dim3(256), 0, stream, x, flags);
  hipLaunchKernelGGL(compact_kernel, dim3(NN / 256), dim3(256), 0, stream, flags, cnt, list, slot);
  hipLaunchKernelGGL(wh_kernel,      dim3(NN / 32),  dim3(256), 0, stream, emb, W, Wh);
  hipLaunchKernelGGL(attn_kernel,    dim3(QBLKS * NSPLIT), dim3(256), 0, stream,
                     Wh, adj, list, cnt, Opart, mpart, lpart);
  hipLaunchKernelGGL(combine_kernel, dim3(4096), dim3(128), 0, stream, Opart, mpart, lpart, h);
  hipLaunchKernelGGL(out_kernel,     dim3(BB),   dim3(128), 0, stream, x, slot, h, out);
}

// Round 2
// 532.476 us; speedup vs baseline: 1.2653x; 1.2653x over previous
//
#include <hip/hip_runtime.h>

#define NN 8192
#define DD 256
#define FF 128
#define BB 4096
#define NSPLIT 8
#define KCHUNK (NN / NSPLIT)   // 1024 keys per split-K chunk
#define QBLKS 128              // ceil(4096/32)

typedef unsigned short ushortT;
typedef __attribute__((ext_vector_type(8))) short bf16x8;
typedef __attribute__((ext_vector_type(4))) float f32x4;

__device__ __forceinline__ ushortT f2bf(float f) {   // fp32 -> bf16 RNE
  unsigned u = __float_as_uint(f);
  return (ushortT)((u + 0x7FFFu + ((u >> 16) & 1u)) >> 16);
}
__device__ __forceinline__ float bf2f(ushortT h) {
  return __uint_as_float(((unsigned)h) << 16);
}

// ---------------- unique(x) compaction ----------------

__global__ __launch_bounds__(256) void init_kernel(int* flags, int* cnt) {
  int i = blockIdx.x * 256 + threadIdx.x;
  flags[i] = 0;
  if (i == 0) *cnt = 0;
}

__global__ __launch_bounds__(256) void scatter_kernel(const int* __restrict__ x, int* flags) {
  int b = blockIdx.x * 256 + threadIdx.x;
  flags[x[b]] = 1;
}

__global__ __launch_bounds__(256) void compact_kernel(const int* __restrict__ flags, int* cnt,
                                                      int* list, int* slot) {
  int i = blockIdx.x * 256 + threadIdx.x;
  if (flags[i]) {
    int pos = atomicAdd(cnt, 1);
    list[pos] = i;
    slot[i] = pos;
  }
}

// ---------------- Wh = embedding @ W, emitted as bf16 hi/lo split ----------------

__global__ __launch_bounds__(256) void wh_kernel(const float* __restrict__ emb,
                                                 const float* __restrict__ W,
                                                 ushortT* __restrict__ Whh,
                                                 ushortT* __restrict__ Whl) {
  __shared__ float Es[32 * 65];
  __shared__ float Ws[64 * 128];
  const int t = threadIdx.x;
  const int r0 = blockIdx.x * 32;
  const int rg = t >> 5;
  const int cg = t & 31;
  float4 acc[4] = {{0,0,0,0},{0,0,0,0},{0,0,0,0},{0,0,0,0}};
  for (int kc = 0; kc < DD; kc += 64) {
    __syncthreads();
    for (int i = 0; i < 8; ++i) {
      int idx = t + 256 * i;
      int r = idx >> 6, k = idx & 63;
      Es[r * 65 + k] = emb[(r0 + r) * DD + kc + k];
    }
    for (int i = 0; i < 8; ++i) {
      int idx = t + 256 * i;
      int kr = idx >> 5, c4 = (idx & 31) * 4;
      *(float4*)&Ws[kr * 128 + c4] = *(const float4*)&W[(kc + kr) * 128 + c4];
    }
    __syncthreads();
    for (int k = 0; k < 64; ++k) {
      float4 b = *(const float4*)&Ws[k * 128 + cg * 4];
#pragma unroll
      for (int i = 0; i < 4; ++i) {
        float a = Es[(rg * 4 + i) * 65 + k];
        acc[i].x += a * b.x; acc[i].y += a * b.y;
        acc[i].z += a * b.z; acc[i].w += a * b.w;
      }
    }
  }
#pragma unroll
  for (int i = 0; i < 4; ++i) {
    int row = r0 + rg * 4 + i;
    float v[4] = {acc[i].x, acc[i].y, acc[i].z, acc[i].w};
    ushort4 hh, ll;
    ushortT* hp = (ushortT*)&hh;
    ushortT* lp = (ushortT*)&ll;
#pragma unroll
    for (int k = 0; k < 4; ++k) {
      ushortT h = f2bf(v[k]);
      hp[k] = h;
      lp[k] = f2bf(v[k] - bf2f(h));
    }
    *(ushort4*)&Whh[row * FF + cg * 4] = hh;
    *(ushort4*)&Whl[row * FF + cg * 4] = ll;
  }
}

// ---------------- WhT = Whh^T (128 x 8192) for PV B-fragments ----------------

__global__ __launch_bounds__(256) void transpose_kernel(const ushortT* __restrict__ A,
                                                        ushortT* __restrict__ At) {
  __shared__ ushortT tile[128 * 136];   // pad 136: b128-aligned rows, bank-rotating
  const int t = threadIdx.x;
  const int r0 = blockIdx.x * 128;
  for (int i = 0; i < 8; ++i) {
    int idx = t + 256 * i;               // 2048 chunks of 8
    int r = idx >> 4, c8 = idx & 15;
    *(bf16x8*)&tile[r * 136 + c8 * 8] = *(const bf16x8*)&A[(r0 + r) * FF + c8 * 8];
  }
  __syncthreads();
  for (int i = 0; i < 8; ++i) {
    int idx = t + 256 * i;               // 128 f x 16 r-chunks
    int f = idx >> 4, r8 = idx & 15;
    bf16x8 v;
#pragma unroll
    for (int u = 0; u < 8; ++u) v[u] = (short)tile[(r8 * 8 + u) * 136 + f];
    *(bf16x8*)&At[(size_t)f * NN + r0 + r8 * 8] = v;
  }
}

// ---------------- MFMA flash attention over masked S (split-K by 8) ----------------
// alpha cancels in row softmax. S = Qhi.Khi + Qlo.Khi + Qhi.Klo (bf16 hi/lo split,
// ~fp32 logit precision). P->bf16 via LDS roundtrip (C-layout -> A-layout).
// V-frags read directly from WhT (global, L2-resident): B[k=key][n=f] needs key-contiguous.
// Layouts (verified, guide §3): A: lane=(quad,c): A[m=c][k=quad*8+j].
//                               B: B[k=quad*8+j][n=c].  C/D: row=quad*4+reg, col=c.

__global__ __launch_bounds__(256) void attn_kernel(
    const ushortT* __restrict__ Whh, const ushortT* __restrict__ Whl,
    const ushortT* __restrict__ WhT, const int* __restrict__ adj,
    const int* __restrict__ list, const int* __restrict__ cntp,
    float* __restrict__ Opart, float* __restrict__ mpart, float* __restrict__ lpart) {
  __shared__ short Ps[8 * 32 * 8];      // [cb][q^swz][j], 16B granules, xor-swizzled
  __shared__ float pm[2][32];           // per-half row max; pm[0] reused as sc
  __shared__ float lsum[32];
  __shared__ float mrow[32], lrow[32];
  __shared__ int nid[32];

  const int t = threadIdx.x;
  const int cnt = *cntp;
  const int qblk = blockIdx.x >> 3, chunk = blockIdx.x & 7;
  const int qbase = qblk * 32;
  if (qbase >= cnt) return;             // uniform: whole block exits

  if (t < 32) {
    nid[t] = list[min(qbase + t, cnt - 1)];   // dup rows for partial block: unused slots
    mrow[t] = -1e30f;
    lrow[t] = 0.f;
  }
  __syncthreads();

  const int w = t >> 6, l = t & 63, quad = l >> 4, c = l & 15;
  const int mt = w >> 1, nth = w & 1;   // wave: m-tile mt, key-half nth
  const int koff = quad * 8;

  // Q fragments in registers for the whole K loop
  const size_t qrow = (size_t)nid[mt * 16 + c] * FF;
  bf16x8 qh[4], ql[4];
#pragma unroll
  for (int ks = 0; ks < 4; ++ks) {
    qh[ks] = *(const bf16x8*)(Whh + qrow + ks * 32 + koff);
    ql[ks] = *(const bf16x8*)(Whl + qrow + ks * 32 + koff);
  }
  size_t arow[4];
#pragma unroll
  for (int r = 0; r < 4; ++r) arow[r] = (size_t)nid[mt * 16 + quad * 4 + r] * NN;

  f32x4 O[4] = {{0,0,0,0},{0,0,0,0},{0,0,0,0},{0,0,0,0}};
  const int kt0 = chunk * KCHUNK;

  for (int kt = kt0; kt < kt0 + KCHUNK; kt += 64) {
    __syncthreads();                                    // B1: Ps/pm/lsum reuse
    // ---- adj masks for this lane's 8 (row,key) cells (coalesced 64B per quad-row) ----
    int av[2][4];
#pragma unroll
    for (int nt2 = 0; nt2 < 2; ++nt2) {
      int ck = kt + (nth * 2 + nt2) * 16 + c;
#pragma unroll
      for (int r = 0; r < 4; ++r) av[nt2][r] = adj[arow[r] + ck];
    }
    // ---- S = Q.K^T, 2 tiles (nt0,nt1), 3-term hi/lo ----
    f32x4 sacc[2];
#pragma unroll
    for (int nt2 = 0; nt2 < 2; ++nt2) {
      int nt = nth * 2 + nt2;
      const ushortT* kh = Whh + (size_t)(kt + nt * 16 + c) * FF + koff;
      const ushortT* kl = Whl + (size_t)(kt + nt * 16 + c) * FF + koff;
      f32x4 a = {0, 0, 0, 0};
#pragma unroll
      for (int ks = 0; ks < 4; ++ks) {
        bf16x8 bh = *(const bf16x8*)(kh + ks * 32);
        bf16x8 bl = *(const bf16x8*)(kl + ks * 32);
        a = __builtin_amdgcn_mfma_f32_16x16x32_bf16(qh[ks], bh, a, 0, 0, 0);
        a = __builtin_amdgcn_mfma_f32_16x16x32_bf16(ql[ks], bh, a, 0, 0, 0);
        a = __builtin_amdgcn_mfma_f32_16x16x32_bf16(qh[ks], bl, a, 0, 0, 0);
      }
      sacc[nt2] = a;
    }
    // ---- masked row-max partials ----
    float rmax[4];
#pragma unroll
    for (int r = 0; r < 4; ++r) {
      float v0 = av[0][r] > 0 ? sacc[0][r] : -1e30f;
      float v1 = av[1][r] > 0 ? sacc[1][r] : -1e30f;
      rmax[r] = fmaxf(v0, v1);
    }
#pragma unroll
    for (int mk = 1; mk <= 8; mk <<= 1)
#pragma unroll
      for (int r = 0; r < 4; ++r) rmax[r] = fmaxf(rmax[r], __shfl_xor(rmax[r], mk, 16));
    if (c == 0) {
#pragma unroll
      for (int r = 0; r < 4; ++r) pm[nth][mt * 16 + quad * 4 + r] = rmax[r];
    }
    if (t < 32) lsum[t] = 0.f;
    __syncthreads();                                    // B2: pm ready
    if (t < 32) {
      float nm = fmaxf(mrow[t], fmaxf(pm[0][t], pm[1][t]));
      pm[0][t] = __expf(mrow[t] - nm);                  // sc (mrow=-1e30 start: exp(0)=1)
      mrow[t] = nm;
    }
    __syncthreads();                                    // B3: sc/mrow ready
    // ---- P = exp(S-m)*mask -> Ps (bf16, A-layout, swizzled); l partials; O rescale ----
    float psl[4];
#pragma unroll
    for (int r = 0; r < 4; ++r) {
      int q = mt * 16 + quad * 4 + r;
      float nm = mrow[q];
      float pr[2];
#pragma unroll
      for (int nt2 = 0; nt2 < 2; ++nt2) {
        float p = av[nt2][r] > 0 ? __expf(sacc[nt2][r] - nm) : 0.f;
        ushortT pb = f2bf(p);
        int key = (nth * 2 + nt2) * 16 + c;
        int cb = key >> 3;
        int g = cb * 32 + (q ^ (cb & 7));
        Ps[g * 8 + (key & 7)] = (short)pb;
        pr[nt2] = bf2f(pb);                             // sum the rounded p for consistency
      }
      psl[r] = pr[0] + pr[1];
    }
    float scr[4];
#pragma unroll
    for (int r = 0; r < 4; ++r) scr[r] = pm[0][mt * 16 + quad * 4 + r];
#pragma unroll
    for (int i = 0; i < 4; ++i)
#pragma unroll
      for (int r = 0; r < 4; ++r) O[i][r] *= scr[r];
#pragma unroll
    for (int mk = 1; mk <= 8; mk <<= 1)
#pragma unroll
      for (int r = 0; r < 4; ++r) psl[r] += __shfl_xor(psl[r], mk, 16);
    if (c == 0) {
#pragma unroll
      for (int r = 0; r < 4; ++r) atomicAdd(&lsum[mt * 16 + quad * 4 + r], psl[r]);
    }
    __syncthreads();                                    // B4: Ps/lsum ready
    if (t < 32) lrow[t] = lrow[t] * pm[0][t] + lsum[t];
    // ---- PV: O += P.V  (A from Ps LDS, B from WhT global) ----
    bf16x8 pa[2];
#pragma unroll
    for (int ks2 = 0; ks2 < 2; ++ks2) {
      int cb = ks2 * 4 + quad;
      int g = cb * 32 + ((mt * 16 + c) ^ (cb & 7));
      pa[ks2] = *(const bf16x8*)&Ps[g * 8];
    }
#pragma unroll
    for (int i = 0; i < 4; ++i) {
      int ft = nth * 4 + i;
      const ushortT* vp = WhT + (size_t)(ft * 16 + c) * NN + kt;
#pragma unroll
      for (int ks2 = 0; ks2 < 2; ++ks2) {
        bf16x8 vb = *(const bf16x8*)(vp + ks2 * 32 + koff);
        O[i] = __builtin_amdgcn_mfma_f32_16x16x32_bf16(pa[ks2], vb, O[i], 0, 0, 0);
      }
    }
  }
  // ---- epilogue ----
  float* Op = Opart + (size_t)chunk * 4096 * FF;
#pragma unroll
  for (int i = 0; i < 4; ++i) {
    int ft = nth * 4 + i;
#pragma unroll
    for (int r = 0; r < 4; ++r)
      Op[(size_t)(qbase + mt * 16 + quad * 4 + r) * FF + ft * 16 + c] = O[i][r];
  }
  if (t < 32) {
    mpart[chunk * 4096 + qbase + t] = mrow[t];
    lpart[chunk * 4096 + qbase + t] = lrow[t];
  }
}

// ---------------- merge split-K partials, normalize, elu ----------------

__global__ __launch_bounds__(128) void combine_kernel(
    const float* __restrict__ Opart, const float* __restrict__ mpart,
    const float* __restrict__ lpart, float* __restrict__ h) {
  const int r = blockIdx.x;
  const int t = threadIdx.x;
  float mstar = -1e30f;
#pragma unroll
  for (int c = 0; c < NSPLIT; ++c) mstar = fmaxf(mstar, mpart[c * 4096 + r]);
  float lstar = 0.f, acc = 0.f;
#pragma unroll
  for (int c = 0; c < NSPLIT; ++c) {
    float wgt = __expf(mpart[c * 4096 + r] - mstar);
    lstar += wgt * lpart[c * 4096 + r];
    acc += wgt * Opart[((size_t)c * 4096 + r) * FF + t];
  }
  float v = acc / fmaxf(lstar, 1e-30f);
  h[r * FF + t] = v > 0.f ? v : expm1f(v);
}

// ---------------- gather by x, L2-normalize ----------------

__global__ __launch_bounds__(128) void out_kernel(const int* __restrict__ x,
                                                  const int* __restrict__ slot,
                                                  const float* __restrict__ h,
                                                  float* __restrict__ out) {
  const int b = blockIdx.x, t = threadIdx.x;
  const int s = slot[x[b]];
  float v = h[s * FF + t];
  float ss = v * v;
#pragma unroll
  for (int wd = 1; wd <= 32; wd <<= 1) ss += __shfl_xor(ss, wd);
  __shared__ float red[2];
  if ((t & 63) == 0) red[t >> 6] = ss;
  __syncthreads();
  float tot = red[0] + red[1];
  float scale = 1.f / fmaxf(sqrtf(tot), 1e-12f);
  out[b * FF + t] = v * scale;
}

// ---------------- launch ----------------

extern "C" void kernel_launch(void* const* d_in, const int* in_sizes, int n_in,
                              void* d_out, int out_size, void* d_ws, size_t ws_size,
                              hipStream_t stream) {
  const int*   x   = (const int*)d_in[0];
  const int*   adj = (const int*)d_in[1];
  const float* emb = (const float*)d_in[2];
  const float* W   = (const float*)d_in[3];
  float* out = (float*)d_out;

  // ws layout (bytes) — total 23,412,740 B, same footprint as the passing R1 layout.
  char* base = (char*)d_ws;
  ushortT* Whh = (ushortT*)(base);                       //  0 .. 2 MB
  ushortT* Whl = (ushortT*)(base + 2097152);             //  2 .. 4 MB (dead after attn)
  float*   h   = (float*)(base + 2097152);               //  aliases Whl (combine/out only)
  ushortT* WhT = (ushortT*)(base + 4194304);             //  4 .. 6 MB
  float* Opart = (float*)(base + 6291456);               //  6 .. 22 MB
  float* mpart = (float*)(base + 23068672);
  float* lpart = (float*)(base + 23199744);
  int*   flags = (int*)(base + 23330816);
  int*   list  = (int*)(base + 23363584);
  int*   slot  = (int*)(base + 23379968);
  int*   cnt   = (int*)(base + 23412736);
  (void)in_sizes; (void)n_in; (void)out_size; (void)ws_size;

  hipLaunchKernelGGL(init_kernel,      dim3(NN / 256), dim3(256), 0, stream, flags, cnt);
  hipLaunchKernelGGL(scatter_kernel,   dim3(BB / 256), dim3(256), 0, stream, x, flags);
  hipLaunchKernelGGL(compact_kernel,   dim3(NN / 256), dim3(256), 0, stream, flags, cnt, list, slot);
  hipLaunchKernelGGL(wh_kernel,        dim3(NN / 32),  dim3(256), 0, stream, emb, W, Whh, Whl);
  hipLaunchKernelGGL(transpose_kernel, dim3(NN / 128), dim3(256), 0, stream, Whh, WhT);
  hipLaunchKernelGGL(attn_kernel,      dim3(QBLKS * NSPLIT), dim3(256), 0, stream,
                     Whh, Whl, WhT, adj, list, cnt, Opart, mpart, lpart);
  hipLaunchKernelGGL(combine_kernel,   dim3(4096), dim3(128), 0, stream, Opart, mpart, lpart, h);
  hipLaunchKernelGGL(out_kernel,       dim3(BB),   dim3(128), 0, stream, x, slot, h, out);
}

// Round 3
// 514.129 us; speedup vs baseline: 1.3105x; 1.0357x over previous
//
#include <hip/hip_runtime.h>

#define NN 8192
#define DD 256
#define FF 128
#define BB 4096
#define NSPLIT 8
#define KCHUNK (NN / NSPLIT)   // 1024 keys per split-K chunk

typedef unsigned short ushortT;
typedef __attribute__((ext_vector_type(8))) short bf16x8;
typedef __attribute__((ext_vector_type(4))) float f32x4;

__device__ __forceinline__ ushortT f2bf(float f) {   // fp32 -> bf16 RNE
  unsigned u = __float_as_uint(f);
  return (ushortT)((u + 0x7FFFu + ((u >> 16) & 1u)) >> 16);
}
__device__ __forceinline__ float bf2f(ushortT h) {
  return __uint_as_float(((unsigned)h) << 16);
}

// ---------------- unique(x) compaction ----------------

__global__ __launch_bounds__(256) void init_kernel(int* flags, int* cnt) {
  int i = blockIdx.x * 256 + threadIdx.x;
  flags[i] = 0;
  if (i == 0) *cnt = 0;
}

__global__ __launch_bounds__(256) void scatter_kernel(const int* __restrict__ x, int* flags) {
  int b = blockIdx.x * 256 + threadIdx.x;
  flags[x[b]] = 1;
}

__global__ __launch_bounds__(256) void compact_kernel(const int* __restrict__ flags, int* cnt,
                                                      int* list, int* slot) {
  int i = blockIdx.x * 256 + threadIdx.x;
  if (flags[i]) {
    int pos = atomicAdd(cnt, 1);
    list[pos] = i;
    slot[i] = pos;
  }
}

// ---------------- Wh = embedding @ W, emitted as bf16 hi/lo split ----------------

__global__ __launch_bounds__(256) void wh_kernel(const float* __restrict__ emb,
                                                 const float* __restrict__ W,
                                                 ushortT* __restrict__ Whh,
                                                 ushortT* __restrict__ Whl) {
  __shared__ float Es[32 * 65];
  __shared__ float Ws[64 * 128];
  const int t = threadIdx.x;
  const int r0 = blockIdx.x * 32;
  const int rg = t >> 5;
  const int cg = t & 31;
  float4 acc[4] = {{0,0,0,0},{0,0,0,0},{0,0,0,0},{0,0,0,0}};
  for (int kc = 0; kc < DD; kc += 64) {
    __syncthreads();
    for (int i = 0; i < 8; ++i) {
      int idx = t + 256 * i;
      int r = idx >> 6, k = idx & 63;
      Es[r * 65 + k] = emb[(r0 + r) * DD + kc + k];
    }
    for (int i = 0; i < 8; ++i) {
      int idx = t + 256 * i;
      int kr = idx >> 5, c4 = (idx & 31) * 4;
      *(float4*)&Ws[kr * 128 + c4] = *(const float4*)&W[(kc + kr) * 128 + c4];
    }
    __syncthreads();
    for (int k = 0; k < 64; ++k) {
      float4 b = *(const float4*)&Ws[k * 128 + cg * 4];
#pragma unroll
      for (int i = 0; i < 4; ++i) {
        float a = Es[(rg * 4 + i) * 65 + k];
        acc[i].x += a * b.x; acc[i].y += a * b.y;
        acc[i].z += a * b.z; acc[i].w += a * b.w;
      }
    }
  }
#pragma unroll
  for (int i = 0; i < 4; ++i) {
    int row = r0 + rg * 4 + i;
    float v[4] = {acc[i].x, acc[i].y, acc[i].z, acc[i].w};
    ushort4 hh, ll;
    ushortT* hp = (ushortT*)&hh;
    ushortT* lp = (ushortT*)&ll;
#pragma unroll
    for (int k = 0; k < 4; ++k) {
      ushortT h = f2bf(v[k]);
      hp[k] = h;
      lp[k] = f2bf(v[k] - bf2f(h));
    }
    *(ushort4*)&Whh[row * FF + cg * 4] = hh;
    *(ushort4*)&Whl[row * FF + cg * 4] = ll;
  }
}

// ---------------- WhT = Whh^T (128 x 8192) for PV B-fragments ----------------

__global__ __launch_bounds__(256) void transpose_kernel(const ushortT* __restrict__ A,
                                                        ushortT* __restrict__ At) {
  __shared__ ushortT tile[128 * 136];
  const int t = threadIdx.x;
  const int r0 = blockIdx.x * 128;
  for (int i = 0; i < 8; ++i) {
    int idx = t + 256 * i;
    int r = idx >> 4, c8 = idx & 15;
    *(bf16x8*)&tile[r * 136 + c8 * 8] = *(const bf16x8*)&A[(r0 + r) * FF + c8 * 8];
  }
  __syncthreads();
  for (int i = 0; i < 8; ++i) {
    int idx = t + 256 * i;
    int f = idx >> 4, r8 = idx & 15;
    bf16x8 v;
#pragma unroll
    for (int u = 0; u < 8; ++u) v[u] = (short)tile[(r8 * 8 + u) * 136 + f];
    *(bf16x8*)&At[(size_t)f * NN + r0 + r8 * 8] = v;
  }
}

// ---------------- barrier-free per-wave MFMA flash attention ----------------
// One wave = one independent 16-row flash tile over one 1024-key chunk.
// No __syncthreads anywhere: softmax state in registers (replicated over the
// 16 c-lanes), row reduce via 16-lane shfl_xor, P C->A layout transform via
// per-wave private LDS (same-wave RAW, compiler-inserted waitcnt).
// Layouts (verified in R2): A[m=lane&15][k=(lane>>4)*8+j]; B[k=(lane>>4)*8+j][n=lane&15];
// C/D: row=(lane>>4)*4+reg, col=lane&15.

__global__ __launch_bounds__(64) void attn_kernel(
    const ushortT* __restrict__ Whh, const ushortT* __restrict__ Whl,
    const ushortT* __restrict__ WhT, const int* __restrict__ adj,
    const int* __restrict__ list, const int* __restrict__ cntp,
    float* __restrict__ Opart, float* __restrict__ mpart, float* __restrict__ lpart) {
  __shared__ short Ps[16 * 72];         // 16 rows x 64 keys, stride 72 (2-way reads: free)
  const int cnt = *cntp;
  const int qt = blockIdx.x >> 3;       // q-tile of 16 rows
  const int chunk = blockIdx.x & 7;
  const int q0 = qt * 16;
  if (q0 >= cnt) return;                // uniform: whole (1-wave) block exits

  const int l = threadIdx.x;
  const int quad = l >> 4, c = l & 15;

  // Q fragments in registers for the whole K loop (A-operand: row = c)
  const int qidc = list[min(q0 + c, cnt - 1)];   // tail rows duplicate cnt-1 (writes land in unused slots)
  const ushortT* qph = Whh + (size_t)qidc * FF + quad * 8;
  const ushortT* qpl = Whl + (size_t)qidc * FF + quad * 8;
  bf16x8 qh[4], ql[4];
#pragma unroll
  for (int ks = 0; ks < 4; ++ks) {
    qh[ks] = *(const bf16x8*)(qph + ks * 32);
    ql[ks] = *(const bf16x8*)(qpl + ks * 32);
  }
  // adj row bases for C-layout rows quad*4+r
  size_t arow[4];
#pragma unroll
  for (int r = 0; r < 4; ++r)
    arow[r] = (size_t)list[min(q0 + quad * 4 + r, cnt - 1)] * NN;

  float m[4], lr[4];
#pragma unroll
  for (int r = 0; r < 4; ++r) { m[r] = -1e30f; lr[r] = 0.f; }
  f32x4 O[8] = {{0,0,0,0},{0,0,0,0},{0,0,0,0},{0,0,0,0},
                {0,0,0,0},{0,0,0,0},{0,0,0,0},{0,0,0,0}};

  const int kt0 = chunk * KCHUNK;
  for (int kt = kt0; kt < kt0 + KCHUNK; kt += 64) {
    // ---- adj masks: 16 loads, each 64B-coalesced per quad-row ----
    int av[4][4];
#pragma unroll
    for (int nt = 0; nt < 4; ++nt)
#pragma unroll
      for (int r = 0; r < 4; ++r) av[nt][r] = adj[arow[r] + kt + nt * 16 + c];

    // ---- S = Q.K^T over 4 key-16 tiles, 3-term hi/lo ----
    f32x4 sacc[4];
#pragma unroll
    for (int nt = 0; nt < 4; ++nt) {
      const ushortT* kh = Whh + (size_t)(kt + nt * 16 + c) * FF + quad * 8;
      const ushortT* kl = Whl + (size_t)(kt + nt * 16 + c) * FF + quad * 8;
      f32x4 a = {0, 0, 0, 0};
#pragma unroll
      for (int ks = 0; ks < 4; ++ks) {
        bf16x8 bh = *(const bf16x8*)(kh + ks * 32);
        bf16x8 bl = *(const bf16x8*)(kl + ks * 32);
        a = __builtin_amdgcn_mfma_f32_16x16x32_bf16(qh[ks], bh, a, 0, 0, 0);
        a = __builtin_amdgcn_mfma_f32_16x16x32_bf16(ql[ks], bh, a, 0, 0, 0);
        a = __builtin_amdgcn_mfma_f32_16x16x32_bf16(qh[ks], bl, a, 0, 0, 0);
      }
      sacc[nt] = a;
    }

    // ---- in-wave masked online softmax (rows quad*4+r, reduce over 16 c-lanes) ----
    float rmax[4];
#pragma unroll
    for (int r = 0; r < 4; ++r) {
      float v = -1e30f;
#pragma unroll
      for (int nt = 0; nt < 4; ++nt) v = fmaxf(v, av[nt][r] > 0 ? sacc[nt][r] : -1e30f);
      rmax[r] = v;
    }
#pragma unroll
    for (int mk = 1; mk <= 8; mk <<= 1)
#pragma unroll
      for (int r = 0; r < 4; ++r) rmax[r] = fmaxf(rmax[r], __shfl_xor(rmax[r], mk, 16));
    float sc[4], psum[4];
#pragma unroll
    for (int r = 0; r < 4; ++r) {
      float nm = fmaxf(m[r], rmax[r]);
      sc[r] = __expf(m[r] - nm);        // first iter: exp(0)=1, lr=0
      m[r] = nm;
      psum[r] = 0.f;
    }
    // P = exp(S-m)*mask -> bf16 -> Ps (C-layout scatter); l sums the rounded p
#pragma unroll
    for (int nt = 0; nt < 4; ++nt)
#pragma unroll
      for (int r = 0; r < 4; ++r) {
        float p = av[nt][r] > 0 ? __expf(sacc[nt][r] - m[r]) : 0.f;
        ushortT pb = f2bf(p);
        Ps[(quad * 4 + r) * 72 + nt * 16 + c] = (short)pb;
        psum[r] += bf2f(pb);
      }
#pragma unroll
    for (int mk = 1; mk <= 8; mk <<= 1)
#pragma unroll
      for (int r = 0; r < 4; ++r) psum[r] += __shfl_xor(psum[r], mk, 16);
#pragma unroll
    for (int r = 0; r < 4; ++r) lr[r] = lr[r] * sc[r] + psum[r];

    // ---- O rescale + PV (A from Ps, B from WhT; same-wave LDS RAW, no barrier) ----
#pragma unroll
    for (int ft = 0; ft < 8; ++ft)
#pragma unroll
      for (int r = 0; r < 4; ++r) O[ft][r] *= sc[r];
    bf16x8 pa[2];
#pragma unroll
    for (int ks2 = 0; ks2 < 2; ++ks2)
      pa[ks2] = *(const bf16x8*)&Ps[c * 72 + ks2 * 32 + quad * 8];
#pragma unroll
    for (int ft = 0; ft < 8; ++ft) {
      const ushortT* vp = WhT + (size_t)(ft * 16 + c) * NN + kt + quad * 8;
#pragma unroll
      for (int ks2 = 0; ks2 < 2; ++ks2) {
        bf16x8 vb = *(const bf16x8*)(vp + ks2 * 32);
        O[ft] = __builtin_amdgcn_mfma_f32_16x16x32_bf16(pa[ks2], vb, O[ft], 0, 0, 0);
      }
    }
  }

  // ---- epilogue ----
  float* Op = Opart + (size_t)chunk * 4096 * FF;
#pragma unroll
  for (int ft = 0; ft < 8; ++ft)
#pragma unroll
    for (int r = 0; r < 4; ++r)
      Op[(size_t)(q0 + quad * 4 + r) * FF + ft * 16 + c] = O[ft][r];
  if (c == 0) {
#pragma unroll
    for (int r = 0; r < 4; ++r) {
      mpart[chunk * 4096 + q0 + quad * 4 + r] = m[r];
      lpart[chunk * 4096 + q0 + quad * 4 + r] = lr[r];
    }
  }
}

// ---------------- merge split-K partials, normalize, elu ----------------

__global__ __launch_bounds__(128) void combine_kernel(
    const float* __restrict__ Opart, const float* __restrict__ mpart,
    const float* __restrict__ lpart, float* __restrict__ h) {
  const int r = blockIdx.x;
  const int t = threadIdx.x;
  float mstar = -1e30f;
#pragma unroll
  for (int c = 0; c < NSPLIT; ++c) mstar = fmaxf(mstar, mpart[c * 4096 + r]);
  float lstar = 0.f, acc = 0.f;
#pragma unroll
  for (int c = 0; c < NSPLIT; ++c) {
    float wgt = __expf(mpart[c * 4096 + r] - mstar);
    lstar += wgt * lpart[c * 4096 + r];
    acc += wgt * Opart[((size_t)c * 4096 + r) * FF + t];
  }
  float v = acc / fmaxf(lstar, 1e-30f);
  h[r * FF + t] = v > 0.f ? v : expm1f(v);
}

// ---------------- gather by x, L2-normalize ----------------

__global__ __launch_bounds__(128) void out_kernel(const int* __restrict__ x,
                                                  const int* __restrict__ slot,
                                                  const float* __restrict__ h,
                                                  float* __restrict__ out) {
  const int b = blockIdx.x, t = threadIdx.x;
  const int s = slot[x[b]];
  float v = h[s * FF + t];
  float ss = v * v;
#pragma unroll
  for (int wd = 1; wd <= 32; wd <<= 1) ss += __shfl_xor(ss, wd);
  __shared__ float red[2];
  if ((t & 63) == 0) red[t >> 6] = ss;
  __syncthreads();
  float tot = red[0] + red[1];
  float scale = 1.f / fmaxf(sqrtf(tot), 1e-12f);
  out[b * FF + t] = v * scale;
}

// ---------------- launch ----------------

extern "C" void kernel_launch(void* const* d_in, const int* in_sizes, int n_in,
                              void* d_out, int out_size, void* d_ws, size_t ws_size,
                              hipStream_t stream) {
  const int*   x   = (const int*)d_in[0];
  const int*   adj = (const int*)d_in[1];
  const float* emb = (const float*)d_in[2];
  const float* W   = (const float*)d_in[3];
  float* out = (float*)d_out;

  char* base = (char*)d_ws;
  ushortT* Whh = (ushortT*)(base);                       //  0 .. 2 MB
  ushortT* Whl = (ushortT*)(base + 2097152);             //  2 .. 4 MB (dead after attn)
  float*   h   = (float*)(base + 2097152);               //  aliases Whl
  ushortT* WhT = (ushortT*)(base + 4194304);             //  4 .. 6 MB
  float* Opart = (float*)(base + 6291456);               //  6 .. 22 MB
  float* mpart = (float*)(base + 23068672);
  float* lpart = (float*)(base + 23199744);
  int*   flags = (int*)(base + 23330816);
  int*   list  = (int*)(base + 23363584);
  int*   slot  = (int*)(base + 23379968);
  int*   cnt   = (int*)(base + 23412736);
  (void)in_sizes; (void)n_in; (void)out_size; (void)ws_size;

  hipLaunchKernelGGL(init_kernel,      dim3(NN / 256), dim3(256), 0, stream, flags, cnt);
  hipLaunchKernelGGL(scatter_kernel,   dim3(BB / 256), dim3(256), 0, stream, x, flags);
  hipLaunchKernelGGL(compact_kernel,   dim3(NN / 256), dim3(256), 0, stream, flags, cnt, list, slot);
  hipLaunchKernelGGL(wh_kernel,        dim3(NN / 32),  dim3(256), 0, stream, emb, W, Whh, Whl);
  hipLaunchKernelGGL(transpose_kernel, dim3(NN / 128), dim3(256), 0, stream, Whh, WhT);
  hipLaunchKernelGGL(attn_kernel,      dim3((BB / 16) * NSPLIT), dim3(64), 0, stream,
                     Whh, Whl, WhT, adj, list, cnt, Opart, mpart, lpart);
  hipLaunchKernelGGL(combine_kernel,   dim3(4096), dim3(128), 0, stream, Opart, mpart, lpart, h);
  hipLaunchKernelGGL(out_kernel,       dim3(BB),   dim3(128), 0, stream, x, slot, h, out);
}

// Round 4
// 463.787 us; speedup vs baseline: 1.4527x; 1.1085x over previous
//
#include <hip/hip_runtime.h>

#define NN 8192
#define DD 256
#define FF 128
#define BB 4096
#define NSPLIT 8
#define KCHUNK (NN / NSPLIT)   // 1024 keys per split-K chunk
#define NITER (KCHUNK / 64)    // 16 key-tiles per chunk

typedef unsigned short ushortT;
typedef __attribute__((ext_vector_type(8))) short bf16x8;
typedef __attribute__((ext_vector_type(4))) float f32x4;

__device__ __forceinline__ ushortT f2bf(float f) {   // fp32 -> bf16 RNE
  unsigned u = __float_as_uint(f);
  return (ushortT)((u + 0x7FFFu + ((u >> 16) & 1u)) >> 16);
}
__device__ __forceinline__ float bf2f(ushortT h) {
  return __uint_as_float(((unsigned)h) << 16);
}

// ---------------- unique(x) compaction ----------------

__global__ __launch_bounds__(256) void init_kernel(int* flags, int* cnt) {
  int i = blockIdx.x * 256 + threadIdx.x;
  flags[i] = 0;
  if (i == 0) *cnt = 0;
}

__global__ __launch_bounds__(256) void scatter_kernel(const int* __restrict__ x, int* flags) {
  int b = blockIdx.x * 256 + threadIdx.x;
  flags[x[b]] = 1;
}

__global__ __launch_bounds__(256) void compact_kernel(const int* __restrict__ flags, int* cnt,
                                                      int* list, int* slot) {
  int i = blockIdx.x * 256 + threadIdx.x;
  if (flags[i]) {
    int pos = atomicAdd(cnt, 1);
    list[pos] = i;
    slot[i] = pos;
  }
}

// ---------------- pack adj rows of unique slots into bitmasks ----------------
// pk[s][k/32] bit (k&31) = adj[list[s]][k] > 0.  3264 rows x 1 KB = ~3.3 MB (L2/L3-resident
// in attn) replacing a 107 MB latency-critical HBM stream.

__global__ __launch_bounds__(256) void pack_kernel(const int* __restrict__ adj,
                                                   const int* __restrict__ list,
                                                   const int* __restrict__ cntp,
                                                   unsigned* __restrict__ pk) {
  const int s = blockIdx.x >> 2;
  const int kc = (blockIdx.x & 3) * 2048;
  if (s >= *cntp) return;                    // uniform per block
  const int w = threadIdx.x >> 6, l = threadIdx.x & 63;
  const int* base = adj + (size_t)list[s] * NN + kc + w * 512;
  unsigned long long* dst = (unsigned long long*)(pk + s * 256 + (kc >> 5) + w * 16);
#pragma unroll
  for (int i = 0; i < 8; ++i) {
    unsigned long long b = __ballot(base[i * 64 + l] > 0);  // bit l = key ...+i*64+l
    if (l == 0) dst[i] = b;
  }
}

// ---------------- Wh = embedding @ W, emitted as bf16 hi/lo split ----------------

__global__ __launch_bounds__(256) void wh_kernel(const float* __restrict__ emb,
                                                 const float* __restrict__ W,
                                                 ushortT* __restrict__ Whh,
                                                 ushortT* __restrict__ Whl) {
  __shared__ float Es[32 * 65];
  __shared__ float Ws[64 * 128];
  const int t = threadIdx.x;
  const int r0 = blockIdx.x * 32;
  const int rg = t >> 5;
  const int cg = t & 31;
  float4 acc[4] = {{0,0,0,0},{0,0,0,0},{0,0,0,0},{0,0,0,0}};
  for (int kc = 0; kc < DD; kc += 64) {
    __syncthreads();
    for (int i = 0; i < 8; ++i) {
      int idx = t + 256 * i;
      int r = idx >> 6, k = idx & 63;
      Es[r * 65 + k] = emb[(r0 + r) * DD + kc + k];
    }
    for (int i = 0; i < 8; ++i) {
      int idx = t + 256 * i;
      int kr = idx >> 5, c4 = (idx & 31) * 4;
      *(float4*)&Ws[kr * 128 + c4] = *(const float4*)&W[(kc + kr) * 128 + c4];
    }
    __syncthreads();
    for (int k = 0; k < 64; ++k) {
      float4 b = *(const float4*)&Ws[k * 128 + cg * 4];
#pragma unroll
      for (int i = 0; i < 4; ++i) {
        float a = Es[(rg * 4 + i) * 65 + k];
        acc[i].x += a * b.x; acc[i].y += a * b.y;
        acc[i].z += a * b.z; acc[i].w += a * b.w;
      }
    }
  }
#pragma unroll
  for (int i = 0; i < 4; ++i) {
    int row = r0 + rg * 4 + i;
    float v[4] = {acc[i].x, acc[i].y, acc[i].z, acc[i].w};
    ushort4 hh, ll;
    ushortT* hp = (ushortT*)&hh;
    ushortT* lp = (ushortT*)&ll;
#pragma unroll
    for (int k = 0; k < 4; ++k) {
      ushortT h = f2bf(v[k]);
      hp[k] = h;
      lp[k] = f2bf(v[k] - bf2f(h));
    }
    *(ushort4*)&Whh[row * FF + cg * 4] = hh;
    *(ushort4*)&Whl[row * FF + cg * 4] = ll;
  }
}

// ---------------- WhT = Whh^T (128 x 8192), 64x64 tiles (256 blocks) ----------------

__global__ __launch_bounds__(256) void transpose_kernel(const ushortT* __restrict__ A,
                                                        ushortT* __restrict__ At) {
  __shared__ ushortT tile[64 * 72];      // chunk-swizzled: (r, cb) at r*72 + ((cb^((r>>3)&7))*8)
  const int t = threadIdx.x;
  const int r0 = (blockIdx.x >> 1) * 64, c0 = (blockIdx.x & 1) * 64;
#pragma unroll
  for (int i = 0; i < 2; ++i) {
    int idx = t + 256 * i;
    int r = idx >> 3, cb = idx & 7;
    *(bf16x8*)&tile[r * 72 + ((cb ^ ((r >> 3) & 7)) * 8)] =
        *(const bf16x8*)&A[(size_t)(r0 + r) * FF + c0 + cb * 8];
  }
  __syncthreads();
#pragma unroll
  for (int i = 0; i < 2; ++i) {
    int idx = t + 256 * i;
    int f = idx >> 3, r8 = idx & 7;
    bf16x8 v;
#pragma unroll
    for (int u = 0; u < 8; ++u) {
      int row = r8 * 8 + u;
      v[u] = (short)tile[row * 72 + (((f >> 3) ^ ((row >> 3) & 7)) * 8) + (f & 7)];
    }
    *(bf16x8*)&At[(size_t)(c0 + f) * NN + r0 + r8 * 8] = v;
  }
}

// ---------------- MFMA flash attention: 4-wave blocks, LDS-dbuf K, bit masks ----------------
// Block = 256 thr = 4 waves, 64 q-rows (wave w: rows w*16..+15), one 1024-key chunk.
// K-tile (64 keys x 128 feats, hi+lo bf16) staged global->regs->LDS, double-buffered,
// ONE barrier per iter: prefetch tile t+1 to regs before compute(t), ds_write to the
// other buffer after. XOR chunk swizzle makes B-frag ds_read_b128 2-way (free).
// Masks from packed bits (L2); V-frags from WhT (global, L2/L3). Softmax in-wave.
// Layouts: A[m=lane&15][k=quad*8+j]; B[k=quad*8+j][n=lane&15]; C/D row=quad*4+reg, col=lane&15.

__global__ __launch_bounds__(256) void attn_kernel(
    const ushortT* __restrict__ Whh, const ushortT* __restrict__ Whl,
    const ushortT* __restrict__ WhT, const unsigned* __restrict__ pk,
    const int* __restrict__ list, const int* __restrict__ cntp,
    float* __restrict__ Opart, float* __restrict__ mpart, float* __restrict__ lpart) {
  __shared__ short Kh[2][64 * 128];
  __shared__ short Kl[2][64 * 128];
  __shared__ short Ps[4][16 * 72];
  __shared__ int nid[64];

  const int cnt = *cntp;
  const int qblk = blockIdx.x >> 3, chunk = blockIdx.x & 7;
  const int q0 = qblk * 64;
  if (q0 >= cnt) return;                 // uniform: whole block exits

  const int t = threadIdx.x;
  if (t < 64) nid[t] = list[min(q0 + t, cnt - 1)];  // tail rows dup cnt-1 (junk slots unused)
  __syncthreads();

  const int w = t >> 6, l = t & 63, quad = l >> 4, c = l & 15;

  // Q fragments in registers for the whole K loop (A-operand: row = c)
  const size_t qr = (size_t)nid[w * 16 + c] * FF;
  bf16x8 qh[4], ql[4];
#pragma unroll
  for (int ks = 0; ks < 4; ++ks) {
    qh[ks] = *(const bf16x8*)(Whh + qr + ks * 32 + quad * 8);
    ql[ks] = *(const bf16x8*)(Whl + qr + ks * 32 + quad * 8);
  }
  int prow[4];
#pragma unroll
  for (int r = 0; r < 4; ++r) prow[r] = min(q0 + w * 16 + quad * 4 + r, cnt - 1);

  float m[4], lr[4];
#pragma unroll
  for (int r = 0; r < 4; ++r) { m[r] = -1e30f; lr[r] = 0.f; }
  f32x4 O[8] = {{0,0,0,0},{0,0,0,0},{0,0,0,0},{0,0,0,0},
                {0,0,0,0},{0,0,0,0},{0,0,0,0},{0,0,0,0}};

  const int kt0 = chunk * KCHUNK;

  // prologue: stage tile 0 into buffer 0
  bf16x8 sgh[4], sgl[4];
  {
    const ushortT* gh = Whh + (size_t)kt0 * FF;
    const ushortT* gl = Whl + (size_t)kt0 * FF;
#pragma unroll
    for (int i = 0; i < 4; ++i) {
      int idx = t + 256 * i;
      sgh[i] = *(const bf16x8*)(gh + idx * 8);
      sgl[i] = *(const bf16x8*)(gl + idx * 8);
    }
#pragma unroll
    for (int i = 0; i < 4; ++i) {
      int idx = t + 256 * i;
      int r = idx >> 4, cb = idx & 15;
      int off = r * 128 + ((cb ^ (r & 7)) * 8);
      *(bf16x8*)&Kh[0][off] = sgh[i];
      *(bf16x8*)&Kl[0][off] = sgl[i];
    }
  }

  for (int it = 0; it < NITER; ++it) {
    const int kt = kt0 + it * 64;
    const int cur = it & 1;
    // ---- prefetch next K-tile into registers (global; hides under compute) ----
    if (it + 1 < NITER) {
      const ushortT* gh = Whh + (size_t)(kt + 64) * FF;
      const ushortT* gl = Whl + (size_t)(kt + 64) * FF;
#pragma unroll
      for (int i = 0; i < 4; ++i) {
        int idx = t + 256 * i;
        sgh[i] = *(const bf16x8*)(gh + idx * 8);
        sgl[i] = *(const bf16x8*)(gl + idx * 8);
      }
    }
    // ---- mask words: 64 bits per row, broadcast loads (L2) ----
    unsigned mw0[4], mw1[4];
#pragma unroll
    for (int r = 0; r < 4; ++r) {
      uint2 mm = *(const uint2*)(pk + (size_t)prow[r] * 256 + (kt >> 5));
      mw0[r] = mm.x; mw1[r] = mm.y;
    }
    __syncthreads();                     // buf[cur] fully staged by all waves

    // ---- S = Q.K^T over 4 key-16 tiles, 3-term hi/lo, K from LDS ----
    f32x4 sacc[4];
#pragma unroll
    for (int nt = 0; nt < 4; ++nt) {
      const int rb = (nt * 16 + c) * 128;
      f32x4 a = {0, 0, 0, 0};
#pragma unroll
      for (int ks = 0; ks < 4; ++ks) {
        const int off = rb + (((ks * 4 + quad) ^ (c & 7)) * 8);
        bf16x8 bh = *(const bf16x8*)&Kh[cur][off];
        bf16x8 bl = *(const bf16x8*)&Kl[cur][off];
        a = __builtin_amdgcn_mfma_f32_16x16x32_bf16(qh[ks], bh, a, 0, 0, 0);
        a = __builtin_amdgcn_mfma_f32_16x16x32_bf16(ql[ks], bh, a, 0, 0, 0);
        a = __builtin_amdgcn_mfma_f32_16x16x32_bf16(qh[ks], bl, a, 0, 0, 0);
      }
      sacc[nt] = a;
    }

    // ---- in-wave masked online softmax ----
    float rmax[4];
#pragma unroll
    for (int r = 0; r < 4; ++r) {
      float v = -1e30f;
#pragma unroll
      for (int nt = 0; nt < 4; ++nt) {
        unsigned bit = ((nt < 2 ? mw0[r] : mw1[r]) >> ((nt & 1) * 16 + c)) & 1u;
        v = fmaxf(v, bit ? sacc[nt][r] : -1e30f);
      }
      rmax[r] = v;
    }
#pragma unroll
    for (int mk = 1; mk <= 8; mk <<= 1)
#pragma unroll
      for (int r = 0; r < 4; ++r) rmax[r] = fmaxf(rmax[r], __shfl_xor(rmax[r], mk, 16));
    float sc[4], psum[4];
#pragma unroll
    for (int r = 0; r < 4; ++r) {
      float nm = fmaxf(m[r], rmax[r]);
      sc[r] = __expf(m[r] - nm);
      m[r] = nm;
      psum[r] = 0.f;
    }
#pragma unroll
    for (int nt = 0; nt < 4; ++nt)
#pragma unroll
      for (int r = 0; r < 4; ++r) {
        unsigned bit = ((nt < 2 ? mw0[r] : mw1[r]) >> ((nt & 1) * 16 + c)) & 1u;
        float p = bit ? __expf(sacc[nt][r] - m[r]) : 0.f;
        ushortT pb = f2bf(p);
        Ps[w][(quad * 4 + r) * 72 + nt * 16 + c] = (short)pb;
        psum[r] += bf2f(pb);
      }
#pragma unroll
    for (int mk = 1; mk <= 8; mk <<= 1)
#pragma unroll
      for (int r = 0; r < 4; ++r) psum[r] += __shfl_xor(psum[r], mk, 16);
#pragma unroll
    for (int r = 0; r < 4; ++r) lr[r] = lr[r] * sc[r] + psum[r];

    // ---- O rescale + PV (A from per-wave Ps, B from WhT global) ----
#pragma unroll
    for (int ft = 0; ft < 8; ++ft)
#pragma unroll
      for (int r = 0; r < 4; ++r) O[ft][r] *= sc[r];
    bf16x8 pa[2];
#pragma unroll
    for (int ks2 = 0; ks2 < 2; ++ks2)
      pa[ks2] = *(const bf16x8*)&Ps[w][c * 72 + ks2 * 32 + quad * 8];
#pragma unroll
    for (int ft = 0; ft < 8; ++ft) {
      const ushortT* vp = WhT + (size_t)(ft * 16 + c) * NN + kt + quad * 8;
#pragma unroll
      for (int ks2 = 0; ks2 < 2; ++ks2) {
        bf16x8 vb = *(const bf16x8*)(vp + ks2 * 32);
        O[ft] = __builtin_amdgcn_mfma_f32_16x16x32_bf16(pa[ks2], vb, O[ft], 0, 0, 0);
      }
    }

    // ---- write prefetched tile into the other buffer (read next iter) ----
    if (it + 1 < NITER) {
#pragma unroll
      for (int i = 0; i < 4; ++i) {
        int idx = t + 256 * i;
        int r = idx >> 4, cb = idx & 15;
        int off = r * 128 + ((cb ^ (r & 7)) * 8);
        *(bf16x8*)&Kh[1 - cur][off] = sgh[i];
        *(bf16x8*)&Kl[1 - cur][off] = sgl[i];
      }
    }
  }

  // ---- epilogue ----
  float* Op = Opart + (size_t)chunk * 4096 * FF;
#pragma unroll
  for (int ft = 0; ft < 8; ++ft)
#pragma unroll
    for (int r = 0; r < 4; ++r)
      Op[(size_t)(q0 + w * 16 + quad * 4 + r) * FF + ft * 16 + c] = O[ft][r];
  if (c == 0) {
#pragma unroll
    for (int r = 0; r < 4; ++r) {
      mpart[chunk * 4096 + q0 + w * 16 + quad * 4 + r] = m[r];
      lpart[chunk * 4096 + q0 + w * 16 + quad * 4 + r] = lr[r];
    }
  }
}

// ---------------- merge split-K partials, normalize, elu ----------------

__global__ __launch_bounds__(128) void combine_kernel(
    const float* __restrict__ Opart, const float* __restrict__ mpart,
    const float* __restrict__ lpart, float* __restrict__ h) {
  const int r = blockIdx.x;
  const int t = threadIdx.x;
  float mstar = -1e30f;
#pragma unroll
  for (int c = 0; c < NSPLIT; ++c) mstar = fmaxf(mstar, mpart[c * 4096 + r]);
  float lstar = 0.f, acc = 0.f;
#pragma unroll
  for (int c = 0; c < NSPLIT; ++c) {
    float wgt = __expf(mpart[c * 4096 + r] - mstar);
    lstar += wgt * lpart[c * 4096 + r];
    acc += wgt * Opart[((size_t)c * 4096 + r) * FF + t];
  }
  float v = acc / fmaxf(lstar, 1e-30f);
  h[r * FF + t] = v > 0.f ? v : expm1f(v);
}

// ---------------- gather by x, L2-normalize ----------------

__global__ __launch_bounds__(128) void out_kernel(const int* __restrict__ x,
                                                  const int* __restrict__ slot,
                                                  const float* __restrict__ h,
                                                  float* __restrict__ out) {
  const int b = blockIdx.x, t = threadIdx.x;
  const int s = slot[x[b]];
  float v = h[s * FF + t];
  float ss = v * v;
#pragma unroll
  for (int wd = 1; wd <= 32; wd <<= 1) ss += __shfl_xor(ss, wd);
  __shared__ float red[2];
  if ((t & 63) == 0) red[t >> 6] = ss;
  __syncthreads();
  float tot = red[0] + red[1];
  float scale = 1.f / fmaxf(sqrtf(tot), 1e-12f);
  out[b * FF + t] = v * scale;
}

// ---------------- launch ----------------

extern "C" void kernel_launch(void* const* d_in, const int* in_sizes, int n_in,
                              void* d_out, int out_size, void* d_ws, size_t ws_size,
                              hipStream_t stream) {
  const int*   x   = (const int*)d_in[0];
  const int*   adj = (const int*)d_in[1];
  const float* emb = (const float*)d_in[2];
  const float* W   = (const float*)d_in[3];
  float* out = (float*)d_out;

  char* base = (char*)d_ws;                              // ~26.4 MB total
  ushortT* Whh = (ushortT*)(base);                       //  0 .. 2 MB
  ushortT* Whl = (ushortT*)(base + 2097152);             //  2 .. 4 MB (dead after attn)
  float*   h   = (float*)(base + 2097152);               //  aliases Whl
  ushortT* WhT = (ushortT*)(base + 4194304);             //  4 .. 6 MB
  float* Opart = (float*)(base + 6291456);               //  6 .. 22.8 MB
  float* mpart = (float*)(base + 23068672);
  float* lpart = (float*)(base + 23199744);
  unsigned* pk = (unsigned*)(base + 23330816);           //  4 MB packed adj bits
  int*   flags = (int*)(base + 27525120);
  int*   list  = (int*)(base + 27557888);
  int*   slot  = (int*)(base + 27574272);
  int*   cnt   = (int*)(base + 27607040);
  (void)in_sizes; (void)n_in; (void)out_size; (void)ws_size;

  hipLaunchKernelGGL(init_kernel,      dim3(NN / 256), dim3(256), 0, stream, flags, cnt);
  hipLaunchKernelGGL(scatter_kernel,   dim3(BB / 256), dim3(256), 0, stream, x, flags);
  hipLaunchKernelGGL(compact_kernel,   dim3(NN / 256), dim3(256), 0, stream, flags, cnt, list, slot);
  hipLaunchKernelGGL(pack_kernel,      dim3(4096 * 4), dim3(256), 0, stream, adj, list, cnt, pk);
  hipLaunchKernelGGL(wh_kernel,        dim3(NN / 32),  dim3(256), 0, stream, emb, W, Whh, Whl);
  hipLaunchKernelGGL(transpose_kernel, dim3((NN / 64) * 2), dim3(256), 0, stream, Whh, WhT);
  hipLaunchKernelGGL(attn_kernel,      dim3((BB / 64) * NSPLIT), dim3(256), 0, stream,
                     Whh, Whl, WhT, pk, list, cnt, Opart, mpart, lpart);
  hipLaunchKernelGGL(combine_kernel,   dim3(4096), dim3(128), 0, stream, Opart, mpart, lpart, h);
  hipLaunchKernelGGL(out_kernel,       dim3(BB),   dim3(128), 0, stream, x, slot, h, out);
}